// Round 1
// baseline (549.651 us; speedup 1.0000x reference)
//
#include <hip/hip_runtime.h>
#include <cstdint>

typedef unsigned short u16;
typedef float    f32x4  __attribute__((ext_vector_type(4)));
typedef __bf16   bf16x8 __attribute__((ext_vector_type(8)));
typedef unsigned int u32x4 __attribute__((ext_vector_type(4)));

#define DIMC   512
#define HEADS  16
#define NTOK   64
#define BWIN   1024
#define HD     32
// per-tensor size of q/k/v in qkv workspace (elements)
#define QKV_ONE (1024u*16u*64u*32u)   // 33554432

__device__ __forceinline__ u16 f2bf(float x) {
  unsigned u = __float_as_uint(x);
  u += 0x7FFFu + ((u >> 16) & 1u);          // round-to-nearest-even
  return (u16)(u >> 16);
}
__device__ __forceinline__ float bf2f(u16 h) {
  return __uint_as_float(((unsigned)h) << 16);
}
__device__ __forceinline__ void gld16(const u16* g, u16* l) {
  // async global->LDS, 16B/lane; LDS dest = wave-uniform base + lane*16
  __builtin_amdgcn_global_load_lds((const __attribute__((address_space(1))) void*)g,
                                   (__attribute__((address_space(3))) void*)l, 16, 0, 0);
}

// ---------------- tiny CPB MLP: bias_table[225][16] ----------------
__global__ void cpb_kernel(const float* __restrict__ w1, const float* __restrict__ b1,
                           const float* __restrict__ w2, float* __restrict__ table) {
  int t  = blockIdx.x;            // 0..224
  int ti = t / 15, tj = t % 15;
  float v0 = (float)(tj - 7) * (8.0f / 7.0f);
  float v1 = (float)(ti - 7) * (8.0f / 7.0f);
  float c0 = copysignf(log2f(fabsf(v0) + 1.0f) / 3.0f, v0);  // /log2(8)
  float c1 = copysignf(log2f(fabsf(v1) + 1.0f) / 3.0f, v1);
  float acc[HEADS];
#pragma unroll
  for (int h = 0; h < HEADS; ++h) acc[h] = 0.f;
  for (int k = threadIdx.x; k < 512; k += 64) {
    float hid = fmaxf(c0 * w1[k] + c1 * w1[512 + k] + b1[k], 0.0f);
#pragma unroll
    for (int h = 0; h < HEADS; ++h) acc[h] += hid * w2[k * HEADS + h];
  }
#pragma unroll
  for (int off = 32; off >= 1; off >>= 1) {
#pragma unroll
    for (int h = 0; h < HEADS; ++h) acc[h] += __shfl_xor(acc[h], off, 64);
  }
  if (threadIdx.x == 0) {
#pragma unroll
    for (int h = 0; h < HEADS; ++h) table[t * HEADS + h] = acc[h];
  }
}

// ------- combined bias: cbias[w][h][i][j] = 16*sigmoid(rpb) + mask[w][i][j] -------
__global__ void cbias_kernel(const float* __restrict__ table, const float* __restrict__ mask,
                             float* __restrict__ cbias) {
  int wh = blockIdx.x; int w = wh >> 4, h = wh & 15;
  const float* mrow = mask + (size_t)w * 4096;
  float* crow = cbias + (size_t)wh * 4096;
  for (int e = threadIdx.x; e < 4096; e += blockDim.x) {
    int i = e >> 6, j = e & 63;
    int dh = (i & 7) - (j & 7);
    int dw = (i >> 3) - (j >> 3);
    int idx = (dh + 7) * 15 + (dw + 7);
    float r = table[idx * HEADS + h];
    float rpb = 16.0f / (1.0f + __expf(-r));
    crow[e] = rpb + mrow[e];
  }
}

// ---------------- fp32 -> bf16 cast (8 elems/thread) ----------------
__global__ void cast_x_kernel(const float* __restrict__ src, u16* __restrict__ dst, int n8) {
  int i = blockIdx.x * blockDim.x + threadIdx.x;
  if (i >= n8) return;
  const f32x4* s4 = (const f32x4*)src;
  f32x4 a = s4[(size_t)2 * i], b = s4[(size_t)2 * i + 1];
  u16 o[8];
#pragma unroll
  for (int j = 0; j < 4; ++j) { o[j] = f2bf(a[j]); o[4 + j] = f2bf(b[j]); }
  *(u32x4*)(dst + (size_t)i * 8) = *(const u32x4*)o;
}

// ------------- transpose+cast: wt[n][k] = bf16(w[k][n]) -------------
__global__ void tcast_kernel(const float* __restrict__ w, u16* __restrict__ wt, int K, int N) {
  int i = blockIdx.x * blockDim.x + threadIdx.x;
  if (i >= K * N) return;
  int n = i / K, k = i % K;
  wt[i] = f2bf(w[(size_t)k * N + n]);
}

// =====================================================================
// 256x256-tile, BK=32, 8-wave, ring-4 LDS pipelined bf16 MFMA GEMM.
//   C = A(MxK) * Bt(NxK)^T
// Pipeline: stage tile t+3 (async gld_lds) while computing tile t.
// One counted s_waitcnt vmcnt(8) + one raw s_barrier per K-tile; never
// drained to 0 in the main loop (T3+T4). LDS reads XOR-swizzled
// (linear gld_lds dest + pre-swizzled global source + swizzled ds_read).
// EPI=0: qkv epilogue (+[q_bias,0,v_bias], scatter to [3][b][h][tok][d] bf16)
// EPI=1: proj epilogue (+proj_b, fp32 row-major out)
// =====================================================================
#define STAGE(slot) do {                                           \
    u16* _sb = lds + (slot) * 16384;                               \
    gld16(ga, _sb + aW);                                           \
    gld16(ga + (size_t)16 * K, _sb + aW + 16 * 32);                \
    gld16(gb, _sb + 8192 + aW);                                    \
    gld16(gb + (size_t)16 * K, _sb + 8192 + aW + 16 * 32);         \
    ga += 32; gb += 32; } while (0)

#define COMPUTE(slot) do {                                         \
    const u16* _cb = lds + (slot) * 16384;                         \
    bf16x8 afr[8], bfr[4];                                         \
    _Pragma("unroll")                                              \
    for (int mt = 0; mt < 8; ++mt) afr[mt] = *(const bf16x8*)(_cb + aoff[mt]); \
    _Pragma("unroll")                                              \
    for (int nt = 0; nt < 4; ++nt) bfr[nt] = *(const bf16x8*)(_cb + boff[nt]); \
    __builtin_amdgcn_s_setprio(1);                                 \
    _Pragma("unroll")                                              \
    for (int mt = 0; mt < 8; ++mt)                                 \
      _Pragma("unroll")                                            \
      for (int nt = 0; nt < 4; ++nt)                               \
        acc[mt][nt] = __builtin_amdgcn_mfma_f32_16x16x32_bf16(afr[mt], bfr[nt], acc[mt][nt], 0, 0, 0); \
    __builtin_amdgcn_s_setprio(0); } while (0)

#define WAITB(n) do {                                              \
    asm volatile("s_waitcnt vmcnt(" #n ")" ::: "memory");          \
    __builtin_amdgcn_s_barrier();                                  \
    asm volatile("" ::: "memory"); } while (0)

template <int EPI>
__global__ __launch_bounds__(512, 2) void gemm8_kernel(
    const u16* __restrict__ A, const u16* __restrict__ Bt,
    const float* __restrict__ bias0, const float* __restrict__ bias1,
    void* __restrict__ outp, int M, int N, int K) {
  extern __shared__ u16 lds[];    // [4 slots][A 256x32 | B 256x32] = 128 KiB
  const int nb = N >> 8;
  // bijective XCD swizzle (gridDim.x % 8 == 0 for both GEMMs: 1536, 512)
  const int cpx = gridDim.x >> 3;
  const int bid = blockIdx.x;
  const int wg = (bid & 7) * cpx + (bid >> 3);
  const int m0 = (wg / nb) << 8;
  const int n0 = (wg % nb) << 8;
  const int tid = threadIdx.x, lane = tid & 63, wid = tid >> 6;
  const int wm = wid >> 2, wn = wid & 3;        // 2x4 wave grid
  const int quad = lane >> 4, li = lane & 15;

  // staging: wave stages A rows [wid*32,+32) and B rows [wid*32,+32), 2 gld16 each.
  // gld_lds writes linearly (base + lane*16) -> pre-swizzle the GLOBAL source col:
  // physical 16B-slot s of row r holds logical slot s ^ (r&3).
  const int srow = lane >> 2;                       // row within 16-row chunk
  const int scol = ((lane & 3) ^ (srow & 3)) << 3;  // pre-swizzled col (elems)
  const u16* ga = A  + (size_t)(m0 + wid * 32 + srow) * K + scol;
  const u16* gb = Bt + (size_t)(n0 + wid * 32 + srow) * K + scol;
  const int aW = wid * 32 * 32;                     // wave chunk base (elems)

  // swizzled ds_read offsets (row&3 == li&3 since frag rows are 16-aligned)
  int aoff[8], boff[4];
#pragma unroll
  for (int mt = 0; mt < 8; ++mt)
    aoff[mt] = (wm * 128 + mt * 16 + li) * 32 + ((quad ^ (li & 3)) << 3);
#pragma unroll
  for (int nt = 0; nt < 4; ++nt)
    boff[nt] = 8192 + (wn * 64 + nt * 16 + li) * 32 + ((quad ^ (li & 3)) << 3);

  const f32x4 z = {0.f, 0.f, 0.f, 0.f};
  f32x4 acc[8][4];
#pragma unroll
  for (int i = 0; i < 8; ++i)
#pragma unroll
    for (int j = 0; j < 4; ++j) acc[i][j] = z;

  // prologue: tiles 0,1,2 in flight; wait tile 0 (8 = tiles 1,2 outstanding)
  STAGE(0); STAGE(1); STAGE(2);
  WAITB(8);

  const int KT = K >> 5;    // 16 for K=512
  for (int t = 0; t < KT - 3; ++t) {
    STAGE((t + 3) & 3);     // slot (t+3)&3 held tile t-1: fully consumed pre-barrier
    COMPUTE(t & 3);
    WAITB(8);               // retire own stores for tile t+1; t+2,t+3 stay in flight
  }
  COMPUTE((KT - 3) & 3);
  WAITB(4);
  COMPUTE((KT - 2) & 3);
  WAITB(0);
  COMPUTE((KT - 1) & 3);

  if (EPI == 0) {
    u16* qkvp = (u16*)outp;
#pragma unroll
    for (int nt = 0; nt < 4; ++nt) {
      int n = n0 + wn * 64 + nt * 16 + li;
      float bv = (n < 512) ? bias0[n] : ((n < 1024) ? 0.f : bias1[n - 1024]);
      int three = n >> 9, h = (n >> 5) & 15, d = n & 31;
#pragma unroll
      for (int mt = 0; mt < 8; ++mt) {
#pragma unroll
        for (int r = 0; r < 4; ++r) {
          int m = m0 + wm * 128 + mt * 16 + quad * 4 + r;
          int b = m >> 6, tk = m & 63;
          size_t dst = (size_t)three * QKV_ONE + (((size_t)(b * 16 + h) * 64 + tk) * 32) + d;
          qkvp[dst] = f2bf(acc[mt][nt][r] + bv);
        }
      }
    }
  } else {
    float* op = (float*)outp;
#pragma unroll
    for (int nt = 0; nt < 4; ++nt) {
      int n = n0 + wn * 64 + nt * 16 + li;
      float bv = bias0[n];
#pragma unroll
      for (int mt = 0; mt < 8; ++mt) {
#pragma unroll
        for (int r = 0; r < 4; ++r) {
          int m = m0 + wm * 128 + mt * 16 + quad * 4 + r;
          op[(size_t)m * N + n] = acc[mt][nt][r] + bv;
        }
      }
    }
  }
}

// ---------------- attention: one block per (b,h) ----------------
__global__ __launch_bounds__(256, 2) void attn_kernel(
    const u16* __restrict__ qkv, const float* __restrict__ cbias,
    const float* __restrict__ lsc, u16* __restrict__ attn_out) {
  __shared__ u16 qs[64 * 40], ks[64 * 40];   // [tok][d], stride 40 (pad)
  __shared__ u16 vt[32 * 72];                // V^T: [d][tok], stride 72
  __shared__ u16 ps[64 * 72];                // P: [row][col], stride 72
  __shared__ float invq[64], invk[64];
  const int bid = blockIdx.x;
  const int b = bid >> 4, h = bid & 15;
  const int tid = threadIdx.x, lane = tid & 63, wid = tid >> 6;
  const int quad = lane >> 4, li = lane & 15;
  const size_t base = (size_t)(b * HEADS + h) * (64 * 32);
  const u16* qp = qkv + base;
  const u16* kp = qp + (size_t)QKV_ONE;
  const u16* vp = qp + (size_t)2 * QKV_ONE;
  {
    int r = tid >> 2, c = (tid & 3) * 8;
    u32x4 q4 = *(const u32x4*)(qp + r * 32 + c);
    u32x4 k4 = *(const u32x4*)(kp + r * 32 + c);
    u32x4 v4 = *(const u32x4*)(vp + r * 32 + c);
    *(u32x4*)(qs + r * 40 + c) = q4;
    *(u32x4*)(ks + r * 40 + c) = k4;
    u16 tmp[8];
    *(u32x4*)tmp = v4;
#pragma unroll
    for (int j = 0; j < 8; ++j) vt[(c + j) * 72 + r] = tmp[j];
  }
  __syncthreads();
  if (tid < 128) {
    int r = tid & 63;
    const u16* src = (tid < 64) ? qs : ks;
    float s = 0.f;
#pragma unroll
    for (int d = 0; d < 32; ++d) { float x = bf2f(src[r * 40 + d]); s += x * x; }
    float inv = rsqrtf(s);
    if (tid < 64) invq[r] = inv; else invk[r] = inv;
  }
  __syncthreads();

  const float scale = __expf(fminf(lsc[h], 4.6051701859880914f));  // exp(min(ls, ln 100))

  // S = q . k^T  (raw, normalize in fp32 after)
  const f32x4 z = {0.f, 0.f, 0.f, 0.f};
  f32x4 sacc[4] = {z, z, z, z};
  bf16x8 qa = *(const bf16x8*)(qs + (wid * 16 + li) * 40 + quad * 8);
#pragma unroll
  for (int nt = 0; nt < 4; ++nt) {
    bf16x8 kb = *(const bf16x8*)(ks + (nt * 16 + li) * 40 + quad * 8);
    sacc[nt] = __builtin_amdgcn_mfma_f32_16x16x32_bf16(qa, kb, sacc[nt], 0, 0, 0);
  }
  const float* cb = cbias + ((size_t)(b & 63) * HEADS + h) * 4096;
  float lg[4][4];
#pragma unroll
  for (int nt = 0; nt < 4; ++nt) {
#pragma unroll
    for (int r = 0; r < 4; ++r) {
      int row = wid * 16 + quad * 4 + r;
      int col = nt * 16 + li;
      lg[nt][r] = sacc[nt][r] * invq[row] * invk[col] * scale + cb[row * 64 + col];
    }
  }
  // softmax per row (cols live in 4 nt-regs x 16 lanes of this quad)
#pragma unroll
  for (int r = 0; r < 4; ++r) {
    float mx = fmaxf(fmaxf(lg[0][r], lg[1][r]), fmaxf(lg[2][r], lg[3][r]));
#pragma unroll
    for (int off = 1; off < 16; off <<= 1) mx = fmaxf(mx, __shfl_xor(mx, off, 64));
    float e[4], s = 0.f;
#pragma unroll
    for (int nt = 0; nt < 4; ++nt) { e[nt] = __expf(lg[nt][r] - mx); s += e[nt]; }
#pragma unroll
    for (int off = 1; off < 16; off <<= 1) s += __shfl_xor(s, off, 64);
    float rs = 1.0f / s;
    int row = wid * 16 + quad * 4 + r;
#pragma unroll
    for (int nt = 0; nt < 4; ++nt) ps[row * 72 + nt * 16 + li] = f2bf(e[nt] * rs);
  }
  // O = P (64x64) @ V (64x32); wave's own rows only -> no barrier needed
  f32x4 oacc[2] = {z, z};
#pragma unroll
  for (int kc = 0; kc < 2; ++kc) {
    bf16x8 pa = *(const bf16x8*)(ps + (wid * 16 + li) * 72 + kc * 32 + quad * 8);
#pragma unroll
    for (int nt = 0; nt < 2; ++nt) {
      bf16x8 vb = *(const bf16x8*)(vt + (nt * 16 + li) * 72 + kc * 32 + quad * 8);
      oacc[nt] = __builtin_amdgcn_mfma_f32_16x16x32_bf16(pa, vb, oacc[nt], 0, 0, 0);
    }
  }
  // write attn_out[b][tok][h*32+d] (bf16, token-major for proj GEMM)
  u16* op = attn_out + ((size_t)b * 64) * DIMC + h * HD;
#pragma unroll
  for (int nt = 0; nt < 2; ++nt) {
#pragma unroll
    for (int r = 0; r < 4; ++r) {
      int row = wid * 16 + quad * 4 + r;
      op[(size_t)row * DIMC + nt * 16 + li] = f2bf(oacc[nt][r]);
    }
  }
}

extern "C" void kernel_launch(void* const* d_in, const int* in_sizes, int n_in,
                              void* d_out, int out_size, void* d_ws, size_t ws_size,
                              hipStream_t stream) {
  const float* x    = (const float*)d_in[0];
  const float* mask = (const float*)d_in[1];
  const float* qkvw = (const float*)d_in[2];
  const float* qb   = (const float*)d_in[3];
  const float* vb   = (const float*)d_in[4];
  const float* lsc  = (const float*)d_in[5];
  const float* w1   = (const float*)d_in[6];
  const float* b1   = (const float*)d_in[7];
  const float* w2   = (const float*)d_in[8];
  const float* pw   = (const float*)d_in[9];
  const float* pb   = (const float*)d_in[10];
  float* out = (float*)d_out;

  char* ws = (char*)d_ws;
  u16*   x_bf    = (u16*)(ws);                      //  67,108,864 B
  u16*   qkv_bf  = (u16*)(ws + 67108864);           // 201,326,592 B
  u16*   attn_o  = x_bf;                            // alias: x consumed by gemm1
  u16*   wqkv_t  = (u16*)(ws + 268435456);          //   1,572,864 B
  u16*   wproj_t = (u16*)(ws + 270008320);          //     524,288 B
  float* table   = (float*)(ws + 270532608);        //      14,400 B
  float* cbias   = (float*)(ws + 270548992);        //  16,777,216 B  (end ~274 MB)

  static int inited = 0;
  if (!inited) {
    hipFuncSetAttribute(reinterpret_cast<const void*>(&gemm8_kernel<0>),
                        hipFuncAttributeMaxDynamicSharedMemorySize, 131072);
    hipFuncSetAttribute(reinterpret_cast<const void*>(&gemm8_kernel<1>),
                        hipFuncAttributeMaxDynamicSharedMemorySize, 131072);
    inited = 1;
  }

  cpb_kernel<<<225, 64, 0, stream>>>(w1, b1, w2, table);
  cbias_kernel<<<1024, 256, 0, stream>>>(table, mask, cbias);
  cast_x_kernel<<<16384, 256, 0, stream>>>(x, x_bf, 65536 * 512 / 8);
  tcast_kernel<<<3072, 256, 0, stream>>>(qkvw, wqkv_t, 512, 1536);
  tcast_kernel<<<1024, 256, 0, stream>>>(pw, wproj_t, 512, 512);
  gemm8_kernel<0><<<1536, 512, 131072, stream>>>(x_bf, wqkv_t, qb, vb, qkv_bf, 65536, 1536, 512);
  attn_kernel<<<16384, 256, 0, stream>>>(qkv_bf, cbias, lsc, attn_o);
  gemm8_kernel<1><<<512, 512, 131072, stream>>>(attn_o, wproj_t, pb, nullptr, out, 65536, 512, 512);
}

// Round 3
// 541.846 us; speedup vs baseline: 1.0144x; 1.0144x over previous
//
#include <hip/hip_runtime.h>
#include <cstdint>

typedef unsigned short u16;
typedef float    f32x4  __attribute__((ext_vector_type(4)));
typedef __bf16   bf16x8 __attribute__((ext_vector_type(8)));
typedef unsigned int u32x4 __attribute__((ext_vector_type(4)));

#define DIMC   512
#define HEADS  16
#define NTOK   64
#define BWIN   1024
#define HD     32
// per-tensor size of q/k/v in qkv workspace (elements)
#define QKV_ONE (1024u*16u*64u*32u)   // 33554432

__device__ __forceinline__ u16 f2bf(float x) {
  unsigned u = __float_as_uint(x);
  u += 0x7FFFu + ((u >> 16) & 1u);          // round-to-nearest-even
  return (u16)(u >> 16);
}
__device__ __forceinline__ float bf2f(u16 h) {
  return __uint_as_float(((unsigned)h) << 16);
}
__device__ __forceinline__ void gld16(const u16* g, u16* l) {
  // async global->LDS, 16B/lane; LDS dest = wave-uniform base + lane*16
  __builtin_amdgcn_global_load_lds((const __attribute__((address_space(1))) void*)g,
                                   (__attribute__((address_space(3))) void*)l, 16, 0, 0);
}

// ---------------- tiny CPB MLP: bias_table[225][16] ----------------
__global__ void cpb_kernel(const float* __restrict__ w1, const float* __restrict__ b1,
                           const float* __restrict__ w2, float* __restrict__ table) {
  int t  = blockIdx.x;            // 0..224
  int ti = t / 15, tj = t % 15;
  float v0 = (float)(tj - 7) * (8.0f / 7.0f);
  float v1 = (float)(ti - 7) * (8.0f / 7.0f);
  float c0 = copysignf(log2f(fabsf(v0) + 1.0f) / 3.0f, v0);  // /log2(8)
  float c1 = copysignf(log2f(fabsf(v1) + 1.0f) / 3.0f, v1);
  float acc[HEADS];
#pragma unroll
  for (int h = 0; h < HEADS; ++h) acc[h] = 0.f;
  for (int k = threadIdx.x; k < 512; k += 64) {
    float hid = fmaxf(c0 * w1[k] + c1 * w1[512 + k] + b1[k], 0.0f);
#pragma unroll
    for (int h = 0; h < HEADS; ++h) acc[h] += hid * w2[k * HEADS + h];
  }
#pragma unroll
  for (int off = 32; off >= 1; off >>= 1) {
#pragma unroll
    for (int h = 0; h < HEADS; ++h) acc[h] += __shfl_xor(acc[h], off, 64);
  }
  if (threadIdx.x == 0) {
#pragma unroll
    for (int h = 0; h < HEADS; ++h) table[t * HEADS + h] = acc[h];
  }
}

// ------- combined bias: cbias[w][h][i][j] = 16*sigmoid(rpb) + mask[w][i][j] -------
__global__ void cbias_kernel(const float* __restrict__ table, const float* __restrict__ mask,
                             float* __restrict__ cbias) {
  int wh = blockIdx.x; int w = wh >> 4, h = wh & 15;
  const float* mrow = mask + (size_t)w * 4096;
  float* crow = cbias + (size_t)wh * 4096;
  for (int e = threadIdx.x; e < 4096; e += blockDim.x) {
    int i = e >> 6, j = e & 63;
    int dh = (i & 7) - (j & 7);
    int dw = (i >> 3) - (j >> 3);
    int idx = (dh + 7) * 15 + (dw + 7);
    float r = table[idx * HEADS + h];
    float rpb = 16.0f / (1.0f + __expf(-r));
    crow[e] = rpb + mrow[e];
  }
}

// ---------------- fp32 -> bf16 cast (8 elems/thread) ----------------
__global__ void cast_x_kernel(const float* __restrict__ src, u16* __restrict__ dst, int n8) {
  int i = blockIdx.x * blockDim.x + threadIdx.x;
  if (i >= n8) return;
  const f32x4* s4 = (const f32x4*)src;
  f32x4 a = s4[(size_t)2 * i], b = s4[(size_t)2 * i + 1];
  u16 o[8];
#pragma unroll
  for (int j = 0; j < 4; ++j) { o[j] = f2bf(a[j]); o[4 + j] = f2bf(b[j]); }
  *(u32x4*)(dst + (size_t)i * 8) = *(const u32x4*)o;
}

// ------------- transpose+cast: wt[n][k] = bf16(w[k][n]) -------------
__global__ void tcast_kernel(const float* __restrict__ w, u16* __restrict__ wt, int K, int N) {
  int i = blockIdx.x * blockDim.x + threadIdx.x;
  if (i >= K * N) return;
  int n = i / K, k = i % K;
  wt[i] = f2bf(w[(size_t)k * N + n]);
}

// =====================================================================
// 256x256-tile, BK=32, 8-wave, ring-4 LDS, fine-phase pipelined GEMM.
//   C = A(MxK) * Bt(NxK)^T
// Per K-tile: 2 fine phases (m201-style): {read A0-3+B0-3 | stage-A |
// bar | lgk0 | prio1 | 16 MFMA | prio0 | bar} then {read A4-7 | stage-B
// | bar | lgk0 | prio1 | 16 MFMA | prio0 | vmcnt(8) | bar}. Counted
// vmcnt: 2 tiles of stores always in flight. LDS swizzle: 16B-slot
// s ^= (row>>1)&3 (row parity already splits bank halves) -> every 8
// consecutive lanes hit all 8 bank-slots once: conflict-free.
// EPI=0: qkv epilogue (+[q_bias,0,v_bias], scatter to [3][b][h][tok][d] bf16)
// EPI=1: proj epilogue (+proj_b, fp32 row-major out)
// =====================================================================
#define STAGE_A(slot) do { u16* _sa = lds + (slot) * 16384;            \
    gld16(ga, _sa + aW); gld16(ga + (size_t)16 * K, _sa + aW + 512);   \
    ga += 32; } while (0)
#define STAGE_B(slot) do { u16* _sbb = lds + (slot) * 16384 + 8192;    \
    gld16(gb, _sbb + aW); gld16(gb + (size_t)16 * K, _sbb + aW + 512); \
    gb += 32; } while (0)
#define VM(n) asm volatile("s_waitcnt vmcnt(" #n ")" ::: "memory")
#define NOPX ((void)0)

#define TILE(slot, SA, SB, WN) do {                                    \
    const u16* _cb = lds + (slot) * 16384;                             \
    bf16x8 afr[4], bfr[4];                                             \
    _Pragma("unroll")                                                  \
    for (int mt = 0; mt < 4; ++mt) afr[mt] = *(const bf16x8*)(_cb + aoff[mt]); \
    _Pragma("unroll")                                                  \
    for (int nt = 0; nt < 4; ++nt) bfr[nt] = *(const bf16x8*)(_cb + boff[nt]); \
    SA;                                                                \
    __builtin_amdgcn_s_barrier();                                      \
    asm volatile("s_waitcnt lgkmcnt(0)" ::: "memory");                 \
    __builtin_amdgcn_s_setprio(1);                                     \
    _Pragma("unroll")                                                  \
    for (int mt = 0; mt < 4; ++mt)                                     \
      _Pragma("unroll")                                                \
      for (int nt = 0; nt < 4; ++nt)                                   \
        acc[mt][nt] = __builtin_amdgcn_mfma_f32_16x16x32_bf16(afr[mt], bfr[nt], acc[mt][nt], 0, 0, 0); \
    __builtin_amdgcn_s_setprio(0);                                     \
    __builtin_amdgcn_s_barrier();                                      \
    _Pragma("unroll")                                                  \
    for (int mt = 0; mt < 4; ++mt) afr[mt] = *(const bf16x8*)(_cb + aoff[4 + mt]); \
    SB;                                                                \
    __builtin_amdgcn_s_barrier();                                      \
    asm volatile("s_waitcnt lgkmcnt(0)" ::: "memory");                 \
    __builtin_amdgcn_s_setprio(1);                                     \
    _Pragma("unroll")                                                  \
    for (int mt = 0; mt < 4; ++mt)                                     \
      _Pragma("unroll")                                                \
      for (int nt = 0; nt < 4; ++nt)                                   \
        acc[4 + mt][nt] = __builtin_amdgcn_mfma_f32_16x16x32_bf16(afr[mt], bfr[nt], acc[4 + mt][nt], 0, 0, 0); \
    __builtin_amdgcn_s_setprio(0);                                     \
    WN;                                                                \
    __builtin_amdgcn_s_barrier();                                      \
  } while (0)

template <int EPI>
__global__ __launch_bounds__(512, 2) void gemm8_kernel(
    const u16* __restrict__ A, const u16* __restrict__ Bt,
    const float* __restrict__ bias0, const float* __restrict__ bias1,
    void* __restrict__ outp, int M, int N, int K) {
  extern __shared__ u16 lds[];    // [4 slots][A 256x32 | B 256x32] = 128 KiB
  const int nb = N >> 8;
  // bijective XCD swizzle (gridDim.x % 8 == 0 for both GEMMs: 1536, 512)
  const int cpx = gridDim.x >> 3;
  const int bid = blockIdx.x;
  const int wg = (bid & 7) * cpx + (bid >> 3);
  const int m0 = (wg / nb) << 8;
  const int n0 = (wg % nb) << 8;
  const int tid = threadIdx.x, lane = tid & 63, wid = tid >> 6;
  const int wm = wid >> 2, wn = wid & 3;        // 2x4 wave grid
  const int quad = lane >> 4, li = lane & 15;

  // staging: wave stages A rows [wid*32,+32) and B rows [wid*32,+32).
  // gld_lds writes linearly (base + lane*16) -> pre-swizzle the GLOBAL
  // source: physical 16B-slot s of row r holds logical slot s ^ ((r>>1)&3).
  const int srow = lane >> 2;                            // row within 16-row chunk
  const int scol = ((lane & 3) ^ ((lane >> 3) & 3)) << 3;  // pre-swizzled col (elems)
  const u16* ga = A  + (size_t)(m0 + wid * 32 + srow) * K + scol;
  const u16* gb = Bt + (size_t)(n0 + wid * 32 + srow) * K + scol;
  const int aW = wid * 32 * 32;                          // wave chunk base (elems)

  // swizzled ds_read offsets; frag rows are 16-aligned so (row>>1)&3 == (li>>1)&3
  int aoff[8], boff[4];
#pragma unroll
  for (int mt = 0; mt < 8; ++mt)
    aoff[mt] = (wm * 128 + mt * 16 + li) * 32 + ((quad ^ ((li >> 1) & 3)) << 3);
#pragma unroll
  for (int nt = 0; nt < 4; ++nt)
    boff[nt] = 8192 + (wn * 64 + nt * 16 + li) * 32 + ((quad ^ ((li >> 1) & 3)) << 3);

  const f32x4 z = {0.f, 0.f, 0.f, 0.f};
  f32x4 acc[8][4];
#pragma unroll
  for (int i = 0; i < 8; ++i)
#pragma unroll
    for (int j = 0; j < 4; ++j) acc[i][j] = z;

  // prologue: tiles 0,1,2 in flight (12 stores); wait to 8 -> tile 0 resident
  STAGE_A(0); STAGE_B(0); STAGE_A(1); STAGE_B(1); STAGE_A(2); STAGE_B(2);
  VM(8);
  __builtin_amdgcn_s_barrier();

  const int KT = K >> 5;    // 16 for K=512
  for (int t = 0; t < KT - 3; ++t) {
    // slot (t+3)&3 held tile t-1: fully consumed before tile t-1's final barrier
    TILE(t & 3, STAGE_A((t + 3) & 3), STAGE_B((t + 3) & 3), VM(8));
  }
  TILE((KT - 3) & 3, NOPX, NOPX, VM(4));
  TILE((KT - 2) & 3, NOPX, NOPX, VM(0));
  TILE((KT - 1) & 3, NOPX, NOPX, NOPX);

  if (EPI == 0) {
    u16* qkvp = (u16*)outp;
#pragma unroll
    for (int nt = 0; nt < 4; ++nt) {
      int n = n0 + wn * 64 + nt * 16 + li;
      float bv = (n < 512) ? bias0[n] : ((n < 1024) ? 0.f : bias1[n - 1024]);
      int three = n >> 9, h = (n >> 5) & 15, d = n & 31;
#pragma unroll
      for (int mt = 0; mt < 8; ++mt) {
#pragma unroll
        for (int r = 0; r < 4; ++r) {
          int m = m0 + wm * 128 + mt * 16 + quad * 4 + r;
          int b = m >> 6, tk = m & 63;
          size_t dst = (size_t)three * QKV_ONE + (((size_t)(b * 16 + h) * 64 + tk) * 32) + d;
          qkvp[dst] = f2bf(acc[mt][nt][r] + bv);
        }
      }
    }
  } else {
    float* op = (float*)outp;
#pragma unroll
    for (int nt = 0; nt < 4; ++nt) {
      int n = n0 + wn * 64 + nt * 16 + li;
      float bv = bias0[n];
#pragma unroll
      for (int mt = 0; mt < 8; ++mt) {
#pragma unroll
        for (int r = 0; r < 4; ++r) {
          int m = m0 + wm * 128 + mt * 16 + quad * 4 + r;
          op[(size_t)m * N + n] = acc[mt][nt][r] + bv;
        }
      }
    }
  }
}

// ---------------- attention: one block per (b,h) ----------------
__global__ __launch_bounds__(256, 2) void attn_kernel(
    const u16* __restrict__ qkv, const float* __restrict__ cbias,
    const float* __restrict__ lsc, u16* __restrict__ attn_out) {
  __shared__ u16 qs[64 * 40], ks[64 * 40];   // [tok][d], stride 40 (pad)
  __shared__ u16 vt[32 * 72];                // V^T: [d][tok], stride 72
  __shared__ u16 ps[64 * 72];                // P: [row][col], stride 72
  __shared__ float invq[64], invk[64];
  const int bid = blockIdx.x;
  const int b = bid >> 4, h = bid & 15;
  const int tid = threadIdx.x, lane = tid & 63, wid = tid >> 6;
  const int quad = lane >> 4, li = lane & 15;
  const size_t base = (size_t)(b * HEADS + h) * (64 * 32);
  const u16* qp = qkv + base;
  const u16* kp = qp + (size_t)QKV_ONE;
  const u16* vp = qp + (size_t)2 * QKV_ONE;
  {
    int r = tid >> 2, c = (tid & 3) * 8;
    u32x4 q4 = *(const u32x4*)(qp + r * 32 + c);
    u32x4 k4 = *(const u32x4*)(kp + r * 32 + c);
    u32x4 v4 = *(const u32x4*)(vp + r * 32 + c);
    *(u32x4*)(qs + r * 40 + c) = q4;
    *(u32x4*)(ks + r * 40 + c) = k4;
    u16 tmp[8];
    *(u32x4*)tmp = v4;
#pragma unroll
    for (int j = 0; j < 8; ++j) vt[(c + j) * 72 + r] = tmp[j];
  }
  __syncthreads();
  if (tid < 128) {
    int r = tid & 63;
    const u16* src = (tid < 64) ? qs : ks;
    float s = 0.f;
#pragma unroll
    for (int d = 0; d < 32; ++d) { float x = bf2f(src[r * 40 + d]); s += x * x; }
    float inv = rsqrtf(s);
    if (tid < 64) invq[r] = inv; else invk[r] = inv;
  }
  __syncthreads();

  const float scale = __expf(fminf(lsc[h], 4.6051701859880914f));  // exp(min(ls, ln 100))

  // S = q . k^T  (raw, normalize in fp32 after)
  const f32x4 z = {0.f, 0.f, 0.f, 0.f};
  f32x4 sacc[4] = {z, z, z, z};
  bf16x8 qa = *(const bf16x8*)(qs + (wid * 16 + li) * 40 + quad * 8);
#pragma unroll
  for (int nt = 0; nt < 4; ++nt) {
    bf16x8 kb = *(const bf16x8*)(ks + (nt * 16 + li) * 40 + quad * 8);
    sacc[nt] = __builtin_amdgcn_mfma_f32_16x16x32_bf16(qa, kb, sacc[nt], 0, 0, 0);
  }
  const float* cb = cbias + ((size_t)(b & 63) * HEADS + h) * 4096;
  float lg[4][4];
#pragma unroll
  for (int nt = 0; nt < 4; ++nt) {
#pragma unroll
    for (int r = 0; r < 4; ++r) {
      int row = wid * 16 + quad * 4 + r;
      int col = nt * 16 + li;
      lg[nt][r] = sacc[nt][r] * invq[row] * invk[col] * scale + cb[row * 64 + col];
    }
  }
  // softmax per row (cols live in 4 nt-regs x 16 lanes of this quad)
#pragma unroll
  for (int r = 0; r < 4; ++r) {
    float mx = fmaxf(fmaxf(lg[0][r], lg[1][r]), fmaxf(lg[2][r], lg[3][r]));
#pragma unroll
    for (int off = 1; off < 16; off <<= 1) mx = fmaxf(mx, __shfl_xor(mx, off, 64));
    float e[4], s = 0.f;
#pragma unroll
    for (int nt = 0; nt < 4; ++nt) { e[nt] = __expf(lg[nt][r] - mx); s += e[nt]; }
#pragma unroll
    for (int off = 1; off < 16; off <<= 1) s += __shfl_xor(s, off, 64);
    float rs = 1.0f / s;
    int row = wid * 16 + quad * 4 + r;
#pragma unroll
    for (int nt = 0; nt < 4; ++nt) ps[row * 72 + nt * 16 + li] = f2bf(e[nt] * rs);
  }
  // O = P (64x64) @ V (64x32); wave's own rows only -> no barrier needed
  f32x4 oacc[2] = {z, z};
#pragma unroll
  for (int kc = 0; kc < 2; ++kc) {
    bf16x8 pa = *(const bf16x8*)(ps + (wid * 16 + li) * 72 + kc * 32 + quad * 8);
#pragma unroll
    for (int nt = 0; nt < 2; ++nt) {
      bf16x8 vb = *(const bf16x8*)(vt + (nt * 16 + li) * 72 + kc * 32 + quad * 8);
      oacc[nt] = __builtin_amdgcn_mfma_f32_16x16x32_bf16(pa, vb, oacc[nt], 0, 0, 0);
    }
  }
  // write attn_out[b][tok][h*32+d] (bf16, token-major for proj GEMM)
  u16* op = attn_out + ((size_t)b * 64) * DIMC + h * HD;
#pragma unroll
  for (int nt = 0; nt < 2; ++nt) {
#pragma unroll
    for (int r = 0; r < 4; ++r) {
      int row = wid * 16 + quad * 4 + r;
      op[(size_t)row * DIMC + nt * 16 + li] = f2bf(oacc[nt][r]);
    }
  }
}

extern "C" void kernel_launch(void* const* d_in, const int* in_sizes, int n_in,
                              void* d_out, int out_size, void* d_ws, size_t ws_size,
                              hipStream_t stream) {
  const float* x    = (const float*)d_in[0];
  const float* mask = (const float*)d_in[1];
  const float* qkvw = (const float*)d_in[2];
  const float* qb   = (const float*)d_in[3];
  const float* vb   = (const float*)d_in[4];
  const float* lsc  = (const float*)d_in[5];
  const float* w1   = (const float*)d_in[6];
  const float* b1   = (const float*)d_in[7];
  const float* w2   = (const float*)d_in[8];
  const float* pw   = (const float*)d_in[9];
  const float* pb   = (const float*)d_in[10];
  float* out = (float*)d_out;

  char* ws = (char*)d_ws;
  u16*   x_bf    = (u16*)(ws);                      //  67,108,864 B
  u16*   qkv_bf  = (u16*)(ws + 67108864);           // 201,326,592 B
  u16*   attn_o  = x_bf;                            // alias: x consumed by gemm1
  u16*   wqkv_t  = (u16*)(ws + 268435456);          //   1,572,864 B
  u16*   wproj_t = (u16*)(ws + 270008320);          //     524,288 B
  float* table   = (float*)(ws + 270532608);        //      14,400 B
  float* cbias   = (float*)(ws + 270548992);        //  16,777,216 B  (end ~274 MB)

  static int inited = 0;
  if (!inited) {
    hipFuncSetAttribute(reinterpret_cast<const void*>(&gemm8_kernel<0>),
                        hipFuncAttributeMaxDynamicSharedMemorySize, 131072);
    hipFuncSetAttribute(reinterpret_cast<const void*>(&gemm8_kernel<1>),
                        hipFuncAttributeMaxDynamicSharedMemorySize, 131072);
    inited = 1;
  }

  cpb_kernel<<<225, 64, 0, stream>>>(w1, b1, w2, table);
  cbias_kernel<<<1024, 256, 0, stream>>>(table, mask, cbias);
  cast_x_kernel<<<16384, 256, 0, stream>>>(x, x_bf, 65536 * 512 / 8);
  tcast_kernel<<<3072, 256, 0, stream>>>(qkvw, wqkv_t, 512, 1536);
  tcast_kernel<<<1024, 256, 0, stream>>>(pw, wproj_t, 512, 512);
  gemm8_kernel<0><<<1536, 512, 131072, stream>>>(x_bf, wqkv_t, qb, vb, qkv_bf, 65536, 1536, 512);
  attn_kernel<<<16384, 256, 0, stream>>>(qkv_bf, cbias, lsc, attn_o);
  gemm8_kernel<1><<<512, 512, 131072, stream>>>(attn_o, wproj_t, pb, nullptr, out, 65536, 512, 512);
}